// Round 16
// baseline (86.964 us; speedup 1.0000x reference)
//
#include <hip/hip_runtime.h>
#include <stdint.h>

// NeRF NewSampler: per-ray inverse-CDF fine sampling (JAX threefry-exact,
// partitionable XOR-fold stream: bits[i] = y0^y1 of cipher((0,42),(0,i))),
// register-only pipeline. 4 RAYS PER WAVE, stage-interleaved (ILP-4) to hide
// sort/search serial latency. Cross-lane ops: DPP where a row-pattern exists,
// ds_swizzle for xor-4/8/16, bpermute for data-dependent gathers.
// Block = 256 threads = 4 waves = 16 rays.
//
// ds_swizzle bit-mode: src = ((lane & and) | or) ^ xor; imm = xor<<10|or<<5|and
// DPP ctrl: quad_perm = p0|p1<<2|p2<<4|p3<<6; row_bcast15=0x142, bcast31=0x143

#define NR 4  // rays per wave

__device__ __forceinline__ uint32_t rotl32(uint32_t x, uint32_t d) {
  return (x << d) | (x >> (32u - d));  // -> v_alignbit_b32
}

// JAX threefry2x32, key (0, 42), ILP-NR: NR counters at once. Returns y0^y1.
__device__ __forceinline__ void threefry2x32_xorN(const uint32_t c[NR],
                                                  uint32_t r[NR]) {
  const uint32_t ks0 = 0u;
  const uint32_t ks1 = 42u;
  const uint32_t ks2 = 0x1BD11BDAu ^ 0u ^ 42u;  // 0x1BD11BF0
  uint32_t a[NR], b[NR];
  #pragma unroll
  for (int i = 0; i < NR; ++i) { a[i] = ks0; b[i] = c[i] + ks1; }
#define TF_RN(rr) { \
    _Pragma("unroll") \
    for (int i = 0; i < NR; ++i) { \
      a[i] += b[i]; b[i] = rotl32(b[i], rr); b[i] ^= a[i]; } }
#define TF_INJ(ka, kb) { \
    _Pragma("unroll") \
    for (int i = 0; i < NR; ++i) { a[i] += (ka); b[i] += (kb); } }
  TF_RN(13) TF_RN(15) TF_RN(26) TF_RN(6)
  TF_INJ(ks1, ks2 + 1u)
  TF_RN(17) TF_RN(29) TF_RN(16) TF_RN(24)
  TF_INJ(ks2, ks0 + 2u)
  TF_RN(13) TF_RN(15) TF_RN(26) TF_RN(6)
  TF_INJ(ks0, ks1 + 3u)
  TF_RN(17) TF_RN(29) TF_RN(16) TF_RN(24)
  TF_INJ(ks1, ks2 + 4u)
  TF_RN(13) TF_RN(15) TF_RN(26) TF_RN(6)
  TF_INJ(ks2, ks0 + 5u)
#undef TF_RN
#undef TF_INJ
  #pragma unroll
  for (int i = 0; i < NR; ++i) r[i] = a[i] ^ b[i];
}

// ---- DPP / swizzle helpers ----
template <int CTRL>
__device__ __forceinline__ uint32_t dppu(uint32_t x) {
  return (uint32_t)__builtin_amdgcn_update_dpp((int)x, (int)x, CTRL, 0xF, 0xF, true);
}
template <int CTRL>
__device__ __forceinline__ float dppf(float x) {
  return __int_as_float(__builtin_amdgcn_update_dpp(
      __float_as_int(x), __float_as_int(x), CTRL, 0xF, 0xF, true));
}
template <int IMM>
__device__ __forceinline__ uint32_t swzu(uint32_t x) {
  return (uint32_t)__builtin_amdgcn_ds_swizzle((int)x, IMM);
}
template <int IMM>
__device__ __forceinline__ float swzf(float x) {
  return __int_as_float(__builtin_amdgcn_ds_swizzle(__float_as_int(x), IMM));
}
template <int J>
__device__ __forceinline__ uint32_t xlu(uint32_t x) {
  if constexpr (J == 1)  return dppu<0xB1>(x);        // quad_perm [1,0,3,2]
  else if constexpr (J == 2) return dppu<0x4E>(x);    // quad_perm [2,3,0,1]
  else if constexpr (J == 32) return (uint32_t)__shfl_xor((int)x, 32);
  else return swzu<(J << 10) | 31>(x);
}
template <int J>
__device__ __forceinline__ float xlf(float x) {
  if constexpr (J == 1)  return dppf<0xB1>(x);
  else if constexpr (J == 2) return dppf<0x4E>(x);
  else if constexpr (J == 32) return __shfl_xor(x, 32);
  else return swzf<(J << 10) | 31>(x);
}

// ---- bitonic sort (ascending), ILP-NR independent u32 streams ----
template <int K, int J>
struct SortStage {
  static __device__ __forceinline__ void run(uint32_t b[NR], int lane) {
    uint32_t p[NR];
    #pragma unroll
    for (int i = 0; i < NR; ++i) p[i] = xlu<J>(b[i]);
    const bool keep_min = (((lane & K) != 0) == ((lane & J) != 0));
    #pragma unroll
    for (int i = 0; i < NR; ++i) {
      const uint32_t mn = b[i] < p[i] ? b[i] : p[i];
      const uint32_t mx = b[i] < p[i] ? p[i] : b[i];
      b[i] = keep_min ? mn : mx;
    }
    if constexpr (J > 1) SortStage<K, J / 2>::run(b, lane);
  }
};
template <int K>
struct SortPass {
  static __device__ __forceinline__ void run(uint32_t b[NR], int lane) {
    SortStage<K, K / 2>::run(b, lane);
    if constexpr (K < 64) SortPass<K * 2>::run(b, lane);
  }
};

// ---- bitonic merge cleanup, ILP-NR on (mlo,mhi) pairs ----
template <int D>
struct MergeStage {
  static __device__ __forceinline__ void run(float mlo[NR], float mhi[NR], int lane) {
    float pl[NR], ph[NR];
    #pragma unroll
    for (int i = 0; i < NR; ++i) { pl[i] = xlf<D>(mlo[i]); ph[i] = xlf<D>(mhi[i]); }
    const bool kmin = ((lane & D) == 0);
    #pragma unroll
    for (int i = 0; i < NR; ++i) {
      mlo[i] = kmin ? fminf(mlo[i], pl[i]) : fmaxf(mlo[i], pl[i]);
      mhi[i] = kmin ? fminf(mhi[i], ph[i]) : fmaxf(mhi[i], ph[i]);
    }
    if constexpr (D > 1) MergeStage<D / 2>::run(mlo, mhi, lane);
  }
};

struct F3 { float x, y, z; };  // 12B per-lane contiguous store

__global__ __launch_bounds__(256) void newsampler_kernel(
    const float* __restrict__ rays_o,
    const float* __restrict__ rays_d,
    const float* __restrict__ s_vals,
    const float* __restrict__ weights,
    float* __restrict__ out,
    int nrays)
{
  const int lane = threadIdx.x & 63;
  const int wv   = threadIdx.x >> 6;
  int rbase = (blockIdx.x * 4 + wv) * NR;
  if (rbase + NR > nrays) rbase = 0;  // nrays % 16 == 0 in practice

  // ---- loads (coalesced, all rays) ----
  float sv[NR], wt[NR];
  #pragma unroll
  for (int i = 0; i < NR; ++i) {
    const uint32_t off = (uint32_t)(rbase + i) * 64u + (uint32_t)lane;
    sv[i] = s_vals[off];
    wt[i] = weights[off];
  }

  // ---- bins ----
  float bin[NR];
  #pragma unroll
  for (int i = 0; i < NR; ++i) {
    const float nx = __shfl_down(sv[i], 1);
    bin[i] = 0.5f * (sv[i] + nx);
  }

  // ---- unnormalized cdf: Sklansky scan (ILP-NR), branchless masked adds ----
  const bool inw = (lane >= 1 && lane <= 62);
  float cw[NR];
  #pragma unroll
  for (int i = 0; i < NR; ++i) cw[i] = inw ? (wt[i] + 1e-6f) : 0.0f;
  { float t[NR];
    #pragma unroll
    for (int i = 0; i < NR; ++i) t[i] = dppf<0xA0>(cw[i]);
    #pragma unroll
    for (int i = 0; i < NR; ++i) cw[i] += (lane & 1) ? t[i] : 0.0f;
    #pragma unroll
    for (int i = 0; i < NR; ++i) t[i] = dppf<0x55>(cw[i]);
    #pragma unroll
    for (int i = 0; i < NR; ++i) cw[i] += (lane & 2) ? t[i] : 0.0f;
    #pragma unroll
    for (int i = 0; i < NR; ++i) t[i] = swzf<0x07B>(cw[i]);
    #pragma unroll
    for (int i = 0; i < NR; ++i) cw[i] += (lane & 4) ? t[i] : 0.0f;
    #pragma unroll
    for (int i = 0; i < NR; ++i) t[i] = swzf<0x0F7>(cw[i]);
    #pragma unroll
    for (int i = 0; i < NR; ++i) cw[i] += (lane & 8) ? t[i] : 0.0f;
    #pragma unroll
    for (int i = 0; i < NR; ++i) t[i] = dppf<0x142>(cw[i]);
    #pragma unroll
    for (int i = 0; i < NR; ++i) cw[i] += (lane & 16) ? t[i] : 0.0f;
    #pragma unroll
    for (int i = 0; i < NR; ++i) t[i] = dppf<0x143>(cw[i]);
    #pragma unroll
    for (int i = 0; i < NR; ++i) cw[i] += (lane & 32) ? t[i] : 0.0f;
  }
  float tot[NR], cwx[NR];
  #pragma unroll
  for (int i = 0; i < NR; ++i) {
    tot[i] = __int_as_float(__builtin_amdgcn_readlane(__float_as_int(cw[i]), 63));
    cwx[i] = (lane < 62) ? cw[i] : 3.0e38f;
  }

  // ---- u bits (XOR-fold threefry), bitonic sort (ILP-NR) ----
  uint32_t ctr[NR], bits[NR];
  #pragma unroll
  for (int i = 0; i < NR; ++i)
    ctr[i] = (uint32_t)(rbase + i) * 64u + (uint32_t)lane;
  threefry2x32_xorN(ctr, bits);
  SortPass<2>::run(bits, lane);
  float ut[NR];
  #pragma unroll
  for (int i = 0; i < NR; ++i) {
    const float u = __uint_as_float((bits[i] >> 9) | 0x3f800000u) - 1.0f;
    ut[i] = u * tot[i];
  }

  // ---- binary search searchsorted(cdf[0:62], 'right') (ILP-NR) ----
  int lo[NR], hi[NR];
  #pragma unroll
  for (int i = 0; i < NR; ++i) { lo[i] = 0; hi[i] = 62; }
  #pragma unroll
  for (int it = 0; it < 6; ++it) {
    #pragma unroll
    for (int i = 0; i < NR; ++i) {
      const int m = (lo[i] + hi[i]) >> 1;
      const float c = __shfl(cwx[i], m);
      const bool le = (c <= ut[i]);
      lo[i] = le ? m : lo[i];
      hi[i] = le ? hi[i] : m;
    }
  }

  float fine[NR];
  #pragma unroll
  for (int i = 0; i < NR; ++i) {
    const float cb = __shfl(cw[i], lo[i]);
    const float ca = __shfl(cw[i], hi[i]);
    const float bb = __shfl(bin[i], lo[i]);
    const float ba = __shfl(bin[i], hi[i]);
    float d = ca - cb;
    if (d < 1e-6f * tot[i]) d = tot[i];
    const float t = (ut[i] - cb) / d;
    fine[i] = bb + t * (ba - bb + 1e-6f);
  }

  // ---- bitonic merge: concat(fine asc, sv desc) (ILP-NR) ----
  float mlo[NR], mhi[NR];
  #pragma unroll
  for (int i = 0; i < NR; ++i) {
    const float svr = xlf<32>(swzf<0x7C1F>(sv[i]));  // sv[63-lane]
    mlo[i] = fminf(fine[i], svr);
    mhi[i] = fmaxf(fine[i], svr);
  }
  MergeStage<32>::run(mlo, mhi, lane);
  // merged[lane] = mlo, merged[64+lane] = mhi (ascending), per ray

  // ---- outputs (u32 offsets: out has 83.9M elements < 2^32) ----
  float* pts = out;
  float* zp  = out + (size_t)nrays * 384;
  float* sp  = zp + (size_t)nrays * 128;

  #pragma unroll
  for (int i = 0; i < NR; ++i) {
    const uint32_t ri = (uint32_t)(rbase + i);
    const float ox = rays_o[ri * 3u + 0u];
    const float oy = rays_o[ri * 3u + 1u];
    const float oz = rays_o[ri * 3u + 2u];
    const float dx = rays_d[ri * 3u + 0u];
    const float dy = rays_d[ri * 3u + 1u];
    const float dz = rays_d[ri * 3u + 2u];

    const uint32_t zbase = ri * 128u + (uint32_t)lane;
    zp[zbase]       = mlo[i];
    zp[zbase + 64u] = mhi[i];
    sp[zbase]       = mlo[i];
    sp[zbase + 64u] = mhi[i];

    const uint32_t pbase = ri * 384u + 3u * (uint32_t)lane;
    F3 a = { ox + dx * mlo[i], oy + dy * mlo[i], oz + dz * mlo[i] };
    F3 b = { ox + dx * mhi[i], oy + dy * mhi[i], oz + dz * mhi[i] };
    *(F3*)(pts + pbase)        = a;
    *(F3*)(pts + pbase + 192u) = b;
  }
}

extern "C" void kernel_launch(void* const* d_in, const int* in_sizes, int n_in,
                              void* d_out, int out_size, void* d_ws, size_t ws_size,
                              hipStream_t stream) {
  const float* rays_o  = (const float*)d_in[0];
  const float* rays_d  = (const float*)d_in[1];
  const float* s_vals  = (const float*)d_in[2];
  const float* weights = (const float*)d_in[3];
  float* out = (float*)d_out;

  const int nrays = in_sizes[2] / 64;       // 131072
  const int rays_per_block = 4 * NR;        // 4 waves x NR rays
  const int blocks = (nrays + rays_per_block - 1) / rays_per_block;

  newsampler_kernel<<<blocks, 256, 0, stream>>>(rays_o, rays_d, s_vals, weights,
                                                out, nrays);
}

// Round 17
// 82.469 us; speedup vs baseline: 1.0545x; 1.0545x over previous
//
#include <hip/hip_runtime.h>
#include <stdint.h>

// NeRF NewSampler: per-ray inverse-CDF fine sampling (JAX threefry-exact,
// partitionable XOR-fold stream: bits[i] = y0^y1 of cipher((0,42),(0,i))),
// register-only pipeline, ILP-2 (2 rays/wave). This round: occupancy push
// (__launch_bounds__(256,6) -> VGPR cap ~85, >=6 waves/SIMD) + nontemporal
// z/s stores. Cross-lane: DPP row-patterns, ds_swizzle xor-4/8/16, bpermute
// for data-dependent gathers. Block = 256 threads = 4 waves = 8 rays.
//
// ds_swizzle bit-mode: src = ((lane & and) | or) ^ xor; imm = xor<<10|or<<5|and
// DPP ctrl: quad_perm = p0|p1<<2|p2<<4|p3<<6; row_bcast15=0x142, bcast31=0x143

__device__ __forceinline__ uint32_t rotl32(uint32_t x, uint32_t d) {
  return (x << d) | (x >> (32u - d));  // -> v_alignbit_b32
}

// JAX threefry2x32, key (0, 42), ILP-2: two counters at once.
__device__ __forceinline__ void threefry2x32_xor2(uint32_t c0, uint32_t c1,
                                                  uint32_t* r0, uint32_t* r1) {
  const uint32_t ks0 = 0u;
  const uint32_t ks1 = 42u;
  const uint32_t ks2 = 0x1BD11BDAu ^ 0u ^ 42u;  // 0x1BD11BF0
  uint32_t a0 = 0u, b0 = c0;
  uint32_t a1 = 0u, b1 = c1;
#define TF_R2(r) { a0 += b0; a1 += b1; b0 = rotl32(b0, r); b1 = rotl32(b1, r); \
                   b0 ^= a0; b1 ^= a1; }
  a0 += ks0; b0 += ks1;  a1 += ks0; b1 += ks1;
  TF_R2(13) TF_R2(15) TF_R2(26) TF_R2(6)
  a0 += ks1; b0 += ks2 + 1u;  a1 += ks1; b1 += ks2 + 1u;
  TF_R2(17) TF_R2(29) TF_R2(16) TF_R2(24)
  a0 += ks2; b0 += ks0 + 2u;  a1 += ks2; b1 += ks0 + 2u;
  TF_R2(13) TF_R2(15) TF_R2(26) TF_R2(6)
  a0 += ks0; b0 += ks1 + 3u;  a1 += ks0; b1 += ks1 + 3u;
  TF_R2(17) TF_R2(29) TF_R2(16) TF_R2(24)
  a0 += ks1; b0 += ks2 + 4u;  a1 += ks1; b1 += ks2 + 4u;
  TF_R2(13) TF_R2(15) TF_R2(26) TF_R2(6)
  a0 += ks2; b0 += ks0 + 5u;  a1 += ks2; b1 += ks0 + 5u;
#undef TF_R2
  *r0 = a0 ^ b0;
  *r1 = a1 ^ b1;
}

// ---- DPP / swizzle helpers ----
template <int CTRL>
__device__ __forceinline__ uint32_t dppu(uint32_t x) {
  return (uint32_t)__builtin_amdgcn_update_dpp((int)x, (int)x, CTRL, 0xF, 0xF, true);
}
template <int CTRL>
__device__ __forceinline__ float dppf(float x) {
  return __int_as_float(__builtin_amdgcn_update_dpp(
      __float_as_int(x), __float_as_int(x), CTRL, 0xF, 0xF, true));
}
template <int IMM>
__device__ __forceinline__ uint32_t swzu(uint32_t x) {
  return (uint32_t)__builtin_amdgcn_ds_swizzle((int)x, IMM);
}
template <int IMM>
__device__ __forceinline__ float swzf(float x) {
  return __int_as_float(__builtin_amdgcn_ds_swizzle(__float_as_int(x), IMM));
}
template <int J>
__device__ __forceinline__ uint32_t xlu(uint32_t x) {
  if constexpr (J == 1)  return dppu<0xB1>(x);        // quad_perm [1,0,3,2]
  else if constexpr (J == 2) return dppu<0x4E>(x);    // quad_perm [2,3,0,1]
  else if constexpr (J == 32) return (uint32_t)__shfl_xor((int)x, 32);
  else return swzu<(J << 10) | 31>(x);
}
template <int J>
__device__ __forceinline__ float xlf(float x) {
  if constexpr (J == 1)  return dppf<0xB1>(x);
  else if constexpr (J == 2) return dppf<0x4E>(x);
  else if constexpr (J == 32) return __shfl_xor(x, 32);
  else return swzf<(J << 10) | 31>(x);
}

// ---- bitonic sort (ascending), ILP-2 ----
template <int K, int J>
struct SortStage {
  static __device__ __forceinline__ void run(uint32_t b[2], int lane) {
    const uint32_t p0 = xlu<J>(b[0]);
    const uint32_t p1 = xlu<J>(b[1]);
    const bool keep_min = (((lane & K) != 0) == ((lane & J) != 0));
    const uint32_t mn0 = b[0] < p0 ? b[0] : p0;
    const uint32_t mx0 = b[0] < p0 ? p0 : b[0];
    const uint32_t mn1 = b[1] < p1 ? b[1] : p1;
    const uint32_t mx1 = b[1] < p1 ? p1 : b[1];
    b[0] = keep_min ? mn0 : mx0;
    b[1] = keep_min ? mn1 : mx1;
    if constexpr (J > 1) SortStage<K, J / 2>::run(b, lane);
  }
};
template <int K>
struct SortPass {
  static __device__ __forceinline__ void run(uint32_t b[2], int lane) {
    SortStage<K, K / 2>::run(b, lane);
    if constexpr (K < 64) SortPass<K * 2>::run(b, lane);
  }
};

// ---- bitonic merge cleanup, ILP-2 on (mlo,mhi) pairs ----
template <int D>
struct MergeStage {
  static __device__ __forceinline__ void run(float mlo[2], float mhi[2], int lane) {
    const float pl0 = xlf<D>(mlo[0]);
    const float ph0 = xlf<D>(mhi[0]);
    const float pl1 = xlf<D>(mlo[1]);
    const float ph1 = xlf<D>(mhi[1]);
    const bool kmin = ((lane & D) == 0);
    mlo[0] = kmin ? fminf(mlo[0], pl0) : fmaxf(mlo[0], pl0);
    mhi[0] = kmin ? fminf(mhi[0], ph0) : fmaxf(mhi[0], ph0);
    mlo[1] = kmin ? fminf(mlo[1], pl1) : fmaxf(mlo[1], pl1);
    mhi[1] = kmin ? fminf(mhi[1], ph1) : fmaxf(mhi[1], ph1);
    if constexpr (D > 1) MergeStage<D / 2>::run(mlo, mhi, lane);
  }
};

struct F3 { float x, y, z; };  // 12B per-lane contiguous store

__global__ __launch_bounds__(256, 6) void newsampler_kernel(
    const float* __restrict__ rays_o,
    const float* __restrict__ rays_d,
    const float* __restrict__ s_vals,
    const float* __restrict__ weights,
    float* __restrict__ out,
    int nrays)
{
  const int lane = threadIdx.x & 63;
  const int wv   = threadIdx.x >> 6;
  int rbase = (blockIdx.x * 4 + wv) * 2;
  if (rbase >= nrays) rbase = 0;  // nrays % 8 == 0 in practice
  const int r[2] = { rbase, rbase + 1 };

  // ---- loads (coalesced, both rays) ----
  float sv[2], wt[2];
  #pragma unroll
  for (int i = 0; i < 2; ++i) {
    const uint32_t off = (uint32_t)r[i] * 64u + (uint32_t)lane;
    sv[i] = s_vals[off];
    wt[i] = weights[off];
  }

  // ---- bins ----
  float bin[2];
  #pragma unroll
  for (int i = 0; i < 2; ++i) {
    const float nx = __shfl_down(sv[i], 1);
    bin[i] = 0.5f * (sv[i] + nx);
  }

  // ---- unnormalized cdf: Sklansky scan (ILP-2), branchless masked adds ----
  const bool inw = (lane >= 1 && lane <= 62);
  float cw[2];
  cw[0] = inw ? (wt[0] + 1e-6f) : 0.0f;
  cw[1] = inw ? (wt[1] + 1e-6f) : 0.0f;
  { float t0, t1;
    t0 = dppf<0xA0>(cw[0]);  t1 = dppf<0xA0>(cw[1]);
    cw[0] += (lane & 1) ? t0 : 0.0f;   cw[1] += (lane & 1) ? t1 : 0.0f;
    t0 = dppf<0x55>(cw[0]);  t1 = dppf<0x55>(cw[1]);
    cw[0] += (lane & 2) ? t0 : 0.0f;   cw[1] += (lane & 2) ? t1 : 0.0f;
    t0 = swzf<0x07B>(cw[0]); t1 = swzf<0x07B>(cw[1]);
    cw[0] += (lane & 4) ? t0 : 0.0f;   cw[1] += (lane & 4) ? t1 : 0.0f;
    t0 = swzf<0x0F7>(cw[0]); t1 = swzf<0x0F7>(cw[1]);
    cw[0] += (lane & 8) ? t0 : 0.0f;   cw[1] += (lane & 8) ? t1 : 0.0f;
    t0 = dppf<0x142>(cw[0]); t1 = dppf<0x142>(cw[1]);
    cw[0] += (lane & 16) ? t0 : 0.0f;  cw[1] += (lane & 16) ? t1 : 0.0f;
    t0 = dppf<0x143>(cw[0]); t1 = dppf<0x143>(cw[1]);
    cw[0] += (lane & 32) ? t0 : 0.0f;  cw[1] += (lane & 32) ? t1 : 0.0f;
  }
  float tot[2], cwx[2];
  #pragma unroll
  for (int i = 0; i < 2; ++i) {
    tot[i] = __int_as_float(__builtin_amdgcn_readlane(__float_as_int(cw[i]), 63));
    cwx[i] = (lane < 62) ? cw[i] : 3.0e38f;
  }

  // ---- u bits (XOR-fold threefry), bitonic sort (ILP-2) ----
  uint32_t bits[2];
  threefry2x32_xor2((uint32_t)r[0] * 64u + (uint32_t)lane,
                    (uint32_t)r[1] * 64u + (uint32_t)lane,
                    &bits[0], &bits[1]);
  SortPass<2>::run(bits, lane);
  float ut[2];
  #pragma unroll
  for (int i = 0; i < 2; ++i) {
    const float u = __uint_as_float((bits[i] >> 9) | 0x3f800000u) - 1.0f;
    ut[i] = u * tot[i];
  }

  // ---- binary search searchsorted(cdf[0:62], 'right') (ILP-2) ----
  int lo0 = 0, hi0 = 62, lo1 = 0, hi1 = 62;
  #pragma unroll
  for (int it = 0; it < 6; ++it) {
    const int m0 = (lo0 + hi0) >> 1;
    const int m1 = (lo1 + hi1) >> 1;
    const float c0 = __shfl(cwx[0], m0);
    const float c1 = __shfl(cwx[1], m1);
    const bool le0 = (c0 <= ut[0]);
    const bool le1 = (c1 <= ut[1]);
    lo0 = le0 ? m0 : lo0;  hi0 = le0 ? hi0 : m0;
    lo1 = le1 ? m1 : lo1;  hi1 = le1 ? hi1 : m1;
  }

  float fine[2];
  {
    const float cb0 = __shfl(cw[0], lo0),  cb1 = __shfl(cw[1], lo1);
    const float ca0 = __shfl(cw[0], hi0),  ca1 = __shfl(cw[1], hi1);
    const float bb0 = __shfl(bin[0], lo0), bb1 = __shfl(bin[1], lo1);
    const float ba0 = __shfl(bin[0], hi0), ba1 = __shfl(bin[1], hi1);
    float d0 = ca0 - cb0;
    float d1 = ca1 - cb1;
    if (d0 < 1e-6f * tot[0]) d0 = tot[0];
    if (d1 < 1e-6f * tot[1]) d1 = tot[1];
    const float t0 = (ut[0] - cb0) / d0;
    const float t1 = (ut[1] - cb1) / d1;
    fine[0] = bb0 + t0 * (ba0 - bb0 + 1e-6f);
    fine[1] = bb1 + t1 * (ba1 - bb1 + 1e-6f);
  }

  // ---- bitonic merge: concat(fine asc, sv desc) (ILP-2) ----
  float mlo[2], mhi[2];
  #pragma unroll
  for (int i = 0; i < 2; ++i) {
    const float svr = xlf<32>(swzf<0x7C1F>(sv[i]));  // sv[63-lane]
    mlo[i] = fminf(fine[i], svr);
    mhi[i] = fmaxf(fine[i], svr);
  }
  MergeStage<32>::run(mlo, mhi, lane);
  // merged[lane] = mlo, merged[64+lane] = mhi (ascending), per ray

  // ---- outputs (u32 offsets; z/s nontemporal: write-once streams) ----
  float* pts = out;
  float* zp  = out + (size_t)nrays * 384;
  float* sp  = zp + (size_t)nrays * 128;

  #pragma unroll
  for (int i = 0; i < 2; ++i) {
    const uint32_t ri = (uint32_t)r[i];
    const float ox = rays_o[ri * 3u + 0u];
    const float oy = rays_o[ri * 3u + 1u];
    const float oz = rays_o[ri * 3u + 2u];
    const float dx = rays_d[ri * 3u + 0u];
    const float dy = rays_d[ri * 3u + 1u];
    const float dz = rays_d[ri * 3u + 2u];

    const uint32_t zbase = ri * 128u + (uint32_t)lane;
    __builtin_nontemporal_store(mlo[i], zp + zbase);
    __builtin_nontemporal_store(mhi[i], zp + zbase + 64u);
    __builtin_nontemporal_store(mlo[i], sp + zbase);
    __builtin_nontemporal_store(mhi[i], sp + zbase + 64u);

    const uint32_t pbase = ri * 384u + 3u * (uint32_t)lane;
    F3 a = { ox + dx * mlo[i], oy + dy * mlo[i], oz + dz * mlo[i] };
    F3 b = { ox + dx * mhi[i], oy + dy * mhi[i], oz + dz * mhi[i] };
    *(F3*)(pts + pbase)        = a;
    *(F3*)(pts + pbase + 192u) = b;
  }
}

extern "C" void kernel_launch(void* const* d_in, const int* in_sizes, int n_in,
                              void* d_out, int out_size, void* d_ws, size_t ws_size,
                              hipStream_t stream) {
  const float* rays_o  = (const float*)d_in[0];
  const float* rays_d  = (const float*)d_in[1];
  const float* s_vals  = (const float*)d_in[2];
  const float* weights = (const float*)d_in[3];
  float* out = (float*)d_out;

  const int nrays = in_sizes[2] / 64;      // 131072
  const int blocks = (nrays + 7) / 8;      // 4 waves/block x 2 rays/wave

  newsampler_kernel<<<blocks, 256, 0, stream>>>(rays_o, rays_d, s_vals, weights,
                                                out, nrays);
}

// Round 18
// 79.961 us; speedup vs baseline: 1.0876x; 1.0314x over previous
//
#include <hip/hip_runtime.h>
#include <stdint.h>

// NeRF NewSampler: per-ray inverse-CDF fine sampling (JAX threefry-exact,
// partitionable XOR-fold stream: bits[i] = y0^y1 of cipher((0,42),(0,i))),
// register-only pipeline, ILP-2 (2 rays/wave), __launch_bounds__(256,6).
// This round: ALL output streams nontemporal (pts too, via aligned(4)
// ext_vector 12B stores) — write-once data should bypass L2 retention.
// Cross-lane: DPP row-patterns, ds_swizzle xor-4/8/16, bpermute for
// data-dependent gathers. Block = 256 threads = 4 waves = 8 rays.
//
// ds_swizzle bit-mode: src = ((lane & and) | or) ^ xor; imm = xor<<10|or<<5|and
// DPP ctrl: quad_perm = p0|p1<<2|p2<<4|p3<<6; row_bcast15=0x142, bcast31=0x143

__device__ __forceinline__ uint32_t rotl32(uint32_t x, uint32_t d) {
  return (x << d) | (x >> (32u - d));  // -> v_alignbit_b32
}

// JAX threefry2x32, key (0, 42), ILP-2: two counters at once.
__device__ __forceinline__ void threefry2x32_xor2(uint32_t c0, uint32_t c1,
                                                  uint32_t* r0, uint32_t* r1) {
  const uint32_t ks0 = 0u;
  const uint32_t ks1 = 42u;
  const uint32_t ks2 = 0x1BD11BDAu ^ 0u ^ 42u;  // 0x1BD11BF0
  uint32_t a0 = 0u, b0 = c0;
  uint32_t a1 = 0u, b1 = c1;
#define TF_R2(r) { a0 += b0; a1 += b1; b0 = rotl32(b0, r); b1 = rotl32(b1, r); \
                   b0 ^= a0; b1 ^= a1; }
  a0 += ks0; b0 += ks1;  a1 += ks0; b1 += ks1;
  TF_R2(13) TF_R2(15) TF_R2(26) TF_R2(6)
  a0 += ks1; b0 += ks2 + 1u;  a1 += ks1; b1 += ks2 + 1u;
  TF_R2(17) TF_R2(29) TF_R2(16) TF_R2(24)
  a0 += ks2; b0 += ks0 + 2u;  a1 += ks2; b1 += ks0 + 2u;
  TF_R2(13) TF_R2(15) TF_R2(26) TF_R2(6)
  a0 += ks0; b0 += ks1 + 3u;  a1 += ks0; b1 += ks1 + 3u;
  TF_R2(17) TF_R2(29) TF_R2(16) TF_R2(24)
  a0 += ks1; b0 += ks2 + 4u;  a1 += ks1; b1 += ks2 + 4u;
  TF_R2(13) TF_R2(15) TF_R2(26) TF_R2(6)
  a0 += ks2; b0 += ks0 + 5u;  a1 += ks2; b1 += ks0 + 5u;
#undef TF_R2
  *r0 = a0 ^ b0;
  *r1 = a1 ^ b1;
}

// ---- DPP / swizzle helpers ----
template <int CTRL>
__device__ __forceinline__ uint32_t dppu(uint32_t x) {
  return (uint32_t)__builtin_amdgcn_update_dpp((int)x, (int)x, CTRL, 0xF, 0xF, true);
}
template <int CTRL>
__device__ __forceinline__ float dppf(float x) {
  return __int_as_float(__builtin_amdgcn_update_dpp(
      __float_as_int(x), __float_as_int(x), CTRL, 0xF, 0xF, true));
}
template <int IMM>
__device__ __forceinline__ uint32_t swzu(uint32_t x) {
  return (uint32_t)__builtin_amdgcn_ds_swizzle((int)x, IMM);
}
template <int IMM>
__device__ __forceinline__ float swzf(float x) {
  return __int_as_float(__builtin_amdgcn_ds_swizzle(__float_as_int(x), IMM));
}
template <int J>
__device__ __forceinline__ uint32_t xlu(uint32_t x) {
  if constexpr (J == 1)  return dppu<0xB1>(x);        // quad_perm [1,0,3,2]
  else if constexpr (J == 2) return dppu<0x4E>(x);    // quad_perm [2,3,0,1]
  else if constexpr (J == 32) return (uint32_t)__shfl_xor((int)x, 32);
  else return swzu<(J << 10) | 31>(x);
}
template <int J>
__device__ __forceinline__ float xlf(float x) {
  if constexpr (J == 1)  return dppf<0xB1>(x);
  else if constexpr (J == 2) return dppf<0x4E>(x);
  else if constexpr (J == 32) return __shfl_xor(x, 32);
  else return swzf<(J << 10) | 31>(x);
}

// ---- bitonic sort (ascending), ILP-2 ----
template <int K, int J>
struct SortStage {
  static __device__ __forceinline__ void run(uint32_t b[2], int lane) {
    const uint32_t p0 = xlu<J>(b[0]);
    const uint32_t p1 = xlu<J>(b[1]);
    const bool keep_min = (((lane & K) != 0) == ((lane & J) != 0));
    const uint32_t mn0 = b[0] < p0 ? b[0] : p0;
    const uint32_t mx0 = b[0] < p0 ? p0 : b[0];
    const uint32_t mn1 = b[1] < p1 ? b[1] : p1;
    const uint32_t mx1 = b[1] < p1 ? p1 : b[1];
    b[0] = keep_min ? mn0 : mx0;
    b[1] = keep_min ? mn1 : mx1;
    if constexpr (J > 1) SortStage<K, J / 2>::run(b, lane);
  }
};
template <int K>
struct SortPass {
  static __device__ __forceinline__ void run(uint32_t b[2], int lane) {
    SortStage<K, K / 2>::run(b, lane);
    if constexpr (K < 64) SortPass<K * 2>::run(b, lane);
  }
};

// ---- bitonic merge cleanup, ILP-2 on (mlo,mhi) pairs ----
template <int D>
struct MergeStage {
  static __device__ __forceinline__ void run(float mlo[2], float mhi[2], int lane) {
    const float pl0 = xlf<D>(mlo[0]);
    const float ph0 = xlf<D>(mhi[0]);
    const float pl1 = xlf<D>(mlo[1]);
    const float ph1 = xlf<D>(mhi[1]);
    const bool kmin = ((lane & D) == 0);
    mlo[0] = kmin ? fminf(mlo[0], pl0) : fmaxf(mlo[0], pl0);
    mhi[0] = kmin ? fminf(mhi[0], ph0) : fmaxf(mhi[0], ph0);
    mlo[1] = kmin ? fminf(mlo[1], pl1) : fmaxf(mlo[1], pl1);
    mhi[1] = kmin ? fminf(mhi[1], ph1) : fmaxf(mhi[1], ph1);
    if constexpr (D > 1) MergeStage<D / 2>::run(mlo, mhi, lane);
  }
};

// 12B vector with 4B alignment (dwordx3 store, no over-alignment assumption)
typedef float f3v __attribute__((ext_vector_type(3), aligned(4)));

__global__ __launch_bounds__(256, 6) void newsampler_kernel(
    const float* __restrict__ rays_o,
    const float* __restrict__ rays_d,
    const float* __restrict__ s_vals,
    const float* __restrict__ weights,
    float* __restrict__ out,
    int nrays)
{
  const int lane = threadIdx.x & 63;
  const int wv   = threadIdx.x >> 6;
  int rbase = (blockIdx.x * 4 + wv) * 2;
  if (rbase >= nrays) rbase = 0;  // nrays % 8 == 0 in practice
  const int r[2] = { rbase, rbase + 1 };

  // ---- loads (coalesced, both rays) ----
  float sv[2], wt[2];
  #pragma unroll
  for (int i = 0; i < 2; ++i) {
    const uint32_t off = (uint32_t)r[i] * 64u + (uint32_t)lane;
    sv[i] = s_vals[off];
    wt[i] = weights[off];
  }

  // ---- bins ----
  float bin[2];
  #pragma unroll
  for (int i = 0; i < 2; ++i) {
    const float nx = __shfl_down(sv[i], 1);
    bin[i] = 0.5f * (sv[i] + nx);
  }

  // ---- unnormalized cdf: Sklansky scan (ILP-2), branchless masked adds ----
  const bool inw = (lane >= 1 && lane <= 62);
  float cw[2];
  cw[0] = inw ? (wt[0] + 1e-6f) : 0.0f;
  cw[1] = inw ? (wt[1] + 1e-6f) : 0.0f;
  { float t0, t1;
    t0 = dppf<0xA0>(cw[0]);  t1 = dppf<0xA0>(cw[1]);
    cw[0] += (lane & 1) ? t0 : 0.0f;   cw[1] += (lane & 1) ? t1 : 0.0f;
    t0 = dppf<0x55>(cw[0]);  t1 = dppf<0x55>(cw[1]);
    cw[0] += (lane & 2) ? t0 : 0.0f;   cw[1] += (lane & 2) ? t1 : 0.0f;
    t0 = swzf<0x07B>(cw[0]); t1 = swzf<0x07B>(cw[1]);
    cw[0] += (lane & 4) ? t0 : 0.0f;   cw[1] += (lane & 4) ? t1 : 0.0f;
    t0 = swzf<0x0F7>(cw[0]); t1 = swzf<0x0F7>(cw[1]);
    cw[0] += (lane & 8) ? t0 : 0.0f;   cw[1] += (lane & 8) ? t1 : 0.0f;
    t0 = dppf<0x142>(cw[0]); t1 = dppf<0x142>(cw[1]);
    cw[0] += (lane & 16) ? t0 : 0.0f;  cw[1] += (lane & 16) ? t1 : 0.0f;
    t0 = dppf<0x143>(cw[0]); t1 = dppf<0x143>(cw[1]);
    cw[0] += (lane & 32) ? t0 : 0.0f;  cw[1] += (lane & 32) ? t1 : 0.0f;
  }
  float tot[2], cwx[2];
  #pragma unroll
  for (int i = 0; i < 2; ++i) {
    tot[i] = __int_as_float(__builtin_amdgcn_readlane(__float_as_int(cw[i]), 63));
    cwx[i] = (lane < 62) ? cw[i] : 3.0e38f;
  }

  // ---- u bits (XOR-fold threefry), bitonic sort (ILP-2) ----
  uint32_t bits[2];
  threefry2x32_xor2((uint32_t)r[0] * 64u + (uint32_t)lane,
                    (uint32_t)r[1] * 64u + (uint32_t)lane,
                    &bits[0], &bits[1]);
  SortPass<2>::run(bits, lane);
  float ut[2];
  #pragma unroll
  for (int i = 0; i < 2; ++i) {
    const float u = __uint_as_float((bits[i] >> 9) | 0x3f800000u) - 1.0f;
    ut[i] = u * tot[i];
  }

  // ---- binary search searchsorted(cdf[0:62], 'right') (ILP-2) ----
  int lo0 = 0, hi0 = 62, lo1 = 0, hi1 = 62;
  #pragma unroll
  for (int it = 0; it < 6; ++it) {
    const int m0 = (lo0 + hi0) >> 1;
    const int m1 = (lo1 + hi1) >> 1;
    const float c0 = __shfl(cwx[0], m0);
    const float c1 = __shfl(cwx[1], m1);
    const bool le0 = (c0 <= ut[0]);
    const bool le1 = (c1 <= ut[1]);
    lo0 = le0 ? m0 : lo0;  hi0 = le0 ? hi0 : m0;
    lo1 = le1 ? m1 : lo1;  hi1 = le1 ? hi1 : m1;
  }

  float fine[2];
  {
    const float cb0 = __shfl(cw[0], lo0),  cb1 = __shfl(cw[1], lo1);
    const float ca0 = __shfl(cw[0], hi0),  ca1 = __shfl(cw[1], hi1);
    const float bb0 = __shfl(bin[0], lo0), bb1 = __shfl(bin[1], lo1);
    const float ba0 = __shfl(bin[0], hi0), ba1 = __shfl(bin[1], hi1);
    float d0 = ca0 - cb0;
    float d1 = ca1 - cb1;
    if (d0 < 1e-6f * tot[0]) d0 = tot[0];
    if (d1 < 1e-6f * tot[1]) d1 = tot[1];
    const float t0 = (ut[0] - cb0) / d0;
    const float t1 = (ut[1] - cb1) / d1;
    fine[0] = bb0 + t0 * (ba0 - bb0 + 1e-6f);
    fine[1] = bb1 + t1 * (ba1 - bb1 + 1e-6f);
  }

  // ---- bitonic merge: concat(fine asc, sv desc) (ILP-2) ----
  float mlo[2], mhi[2];
  #pragma unroll
  for (int i = 0; i < 2; ++i) {
    const float svr = xlf<32>(swzf<0x7C1F>(sv[i]));  // sv[63-lane]
    mlo[i] = fminf(fine[i], svr);
    mhi[i] = fmaxf(fine[i], svr);
  }
  MergeStage<32>::run(mlo, mhi, lane);
  // merged[lane] = mlo, merged[64+lane] = mhi (ascending), per ray

  // ---- outputs: ALL streams nontemporal (write-once) ----
  float* pts = out;
  float* zp  = out + (size_t)nrays * 384;
  float* sp  = zp + (size_t)nrays * 128;

  #pragma unroll
  for (int i = 0; i < 2; ++i) {
    const uint32_t ri = (uint32_t)r[i];
    const float ox = rays_o[ri * 3u + 0u];
    const float oy = rays_o[ri * 3u + 1u];
    const float oz = rays_o[ri * 3u + 2u];
    const float dx = rays_d[ri * 3u + 0u];
    const float dy = rays_d[ri * 3u + 1u];
    const float dz = rays_d[ri * 3u + 2u];

    const uint32_t zbase = ri * 128u + (uint32_t)lane;
    __builtin_nontemporal_store(mlo[i], zp + zbase);
    __builtin_nontemporal_store(mhi[i], zp + zbase + 64u);
    __builtin_nontemporal_store(mlo[i], sp + zbase);
    __builtin_nontemporal_store(mhi[i], sp + zbase + 64u);

    const uint32_t pbase = ri * 384u + 3u * (uint32_t)lane;
    f3v a = { ox + dx * mlo[i], oy + dy * mlo[i], oz + dz * mlo[i] };
    f3v b = { ox + dx * mhi[i], oy + dy * mhi[i], oz + dz * mhi[i] };
    __builtin_nontemporal_store(a, (f3v*)(pts + pbase));
    __builtin_nontemporal_store(b, (f3v*)(pts + pbase + 192u));
  }
}

extern "C" void kernel_launch(void* const* d_in, const int* in_sizes, int n_in,
                              void* d_out, int out_size, void* d_ws, size_t ws_size,
                              hipStream_t stream) {
  const float* rays_o  = (const float*)d_in[0];
  const float* rays_d  = (const float*)d_in[1];
  const float* s_vals  = (const float*)d_in[2];
  const float* weights = (const float*)d_in[3];
  float* out = (float*)d_out;

  const int nrays = in_sizes[2] / 64;      // 131072
  const int blocks = (nrays + 7) / 8;      // 4 waves/block x 2 rays/wave

  newsampler_kernel<<<blocks, 256, 0, stream>>>(rays_o, rays_d, s_vals, weights,
                                                out, nrays);
}